// Round 1
// baseline (249.057 us; speedup 1.0000x reference)
//
#include <hip/hip_runtime.h>

#define DEV __device__ __forceinline__

typedef _Float16 f16;
typedef _Float16 f16x8 __attribute__((ext_vector_type(8)));
typedef _Float16 f16x4 __attribute__((ext_vector_type(4)));
typedef float f32x4 __attribute__((ext_vector_type(4)));

static constexpr int NB = 16;       // batch
static constexpr int NC = 256;      // channels
static constexpr int HW = 1024;     // h*w
static constexpr int NG = 32;       // groups
static constexpr int CPG = 8;       // channels per group
static constexpr int NH = 8;        // heads
static constexpr int HD = 64;       // head dim
static constexpr int INNER = 512;   // heads*head_dim
static constexpr int TD = 1024;     // time-embedding dim

DEV f32x4 mfma16(f16x8 a, f16x8 b, f32x4 c) {
    return __builtin_amdgcn_mfma_f32_16x16x32_f16(a, b, c, 0, 0, 0);
}

// ---------------- GroupNorm: per-(b,g) mean/rstd ----------------
__global__ void gn_stats_k(const float* __restrict__ x, float* __restrict__ stats) {
    int bg = blockIdx.x;  // b*NG + g
    const float4* p = reinterpret_cast<const float4*>(x) + (size_t)bg * (CPG * HW / 4);
    float s = 0.f, ss = 0.f;
    for (int i = threadIdx.x; i < CPG * HW / 4; i += 256) {
        float4 v = p[i];
        s  += v.x + v.y + v.z + v.w;
        ss += v.x * v.x + v.y * v.y + v.z * v.z + v.w * v.w;
    }
    #pragma unroll
    for (int o = 32; o > 0; o >>= 1) {
        s  += __shfl_xor(s, o);
        ss += __shfl_xor(ss, o);
    }
    __shared__ float rs[4], rss[4];
    int wid = threadIdx.x >> 6;
    if ((threadIdx.x & 63) == 0) { rs[wid] = s; rss[wid] = ss; }
    __syncthreads();
    if (threadIdx.x == 0) {
        s  = rs[0] + rs[1] + rs[2] + rs[3];
        ss = rss[0] + rss[1] + rss[2] + rss[3];
        const float inv_n = 1.f / (float)(CPG * HW);
        float mean = s * inv_n;
        float var  = ss * inv_n - mean * mean;
        stats[bg * 2]     = mean;
        stats[bg * 2 + 1] = rsqrtf(var + 1e-5f);
    }
}

// ---------------- GroupNorm apply + transpose -> xnT[b][m][c] (f16) ----------------
__global__ void gn_apply_k(const float* __restrict__ x, const float* __restrict__ stats,
                           const float* __restrict__ nw, const float* __restrict__ nb,
                           f16* __restrict__ xnT) {
    int b = blockIdx.y;
    int m = blockIdx.x * 256 + threadIdx.x;
    const float* xb = x + (size_t)b * NC * HW + m;
    f16* op = xnT + ((size_t)b * HW + m) * NC;
    for (int c0 = 0; c0 < NC; c0 += 4) {
        f16x4 h;
        #pragma unroll
        for (int j = 0; j < 4; ++j) {
            int c = c0 + j;
            float mean = stats[(b * NG + (c >> 3)) * 2];
            float rstd = stats[(b * NG + (c >> 3)) * 2 + 1];
            float v = xb[(size_t)c * HW];
            h[j] = (f16)(((v - mean) * rstd) * nw[c] + nb[c]);
        }
        *reinterpret_cast<f16x4*>(op + c0) = h;
    }
}

// ---------------- fp32 -> f16 weight conversion ----------------
__global__ void conv_w_k(const float* __restrict__ a, const float* __restrict__ bw,
                         f16* __restrict__ wa, f16* __restrict__ wb) {
    int i = blockIdx.x * 256 + threadIdx.x;  // float4 index
    const int N1 = 3 * INNER * NC / 4;       // 98304
    float4 v;
    f16* dst;
    if (i < N1) { v = reinterpret_cast<const float4*>(a)[i];      dst = wa + (size_t)i * 4; }
    else        { v = reinterpret_cast<const float4*>(bw)[i - N1]; dst = wb + (size_t)(i - N1) * 4; }
    f16x4 h4 = {(f16)v.x, (f16)v.y, (f16)v.z, (f16)v.w};
    *reinterpret_cast<f16x4*>(dst) = h4;
}

// ---------------- QKV GEMM: qkv[o,m] = in_w[o,:] . xn[b,:,m], scatter to q/k/v ----------------
__global__ __launch_bounds__(256) void gemm_qkv_k(
        const f16* __restrict__ wA, const f16* __restrict__ xnT,
        const float* __restrict__ bias,
        f16* __restrict__ qT, f16* __restrict__ kT, f16* __restrict__ vv) {
    int b  = blockIdx.z;
    int o0 = blockIdx.x * 128;
    int m0 = blockIdx.y * 128;
    int wid  = threadIdx.x >> 6;
    int lane = threadIdx.x & 63;
    int wr = (wid >> 1) * 64, wc = (wid & 1) * 64;
    int lr = lane & 15, lg = lane >> 4;

    const f16* A  = wA  + (size_t)(o0 + wr + lr) * NC + lg * 8;
    const f16* Bp = xnT + ((size_t)b * HW + m0 + wc + lr) * NC + lg * 8;

    const f32x4 fzero = {0.f, 0.f, 0.f, 0.f};
    f32x4 acc[4][4];
    #pragma unroll
    for (int i = 0; i < 4; ++i) {
        #pragma unroll
        for (int j = 0; j < 4; ++j) acc[i][j] = fzero;
    }

    for (int k0 = 0; k0 < NC; k0 += 32) {
        f16x8 af[4], bf[4];
        #pragma unroll
        for (int i = 0; i < 4; ++i)
            af[i] = *reinterpret_cast<const f16x8*>(A + (size_t)i * 16 * NC + k0);
        #pragma unroll
        for (int j = 0; j < 4; ++j)
            bf[j] = *reinterpret_cast<const f16x8*>(Bp + (size_t)j * 16 * NC + k0);
        #pragma unroll
        for (int i = 0; i < 4; ++i) {
            #pragma unroll
            for (int j = 0; j < 4; ++j)
                acc[i][j] = mfma16(af[i], bf[j], acc[i][j]);
        }
    }

    #pragma unroll
    for (int i = 0; i < 4; ++i) {
        int ob = o0 + wr + i * 16 + lg * 4;  // first of 4 consecutive output rows
        #pragma unroll
        for (int j = 0; j < 4; ++j) {
            int m = m0 + wc + j * 16 + lr;
            float v0 = acc[i][j][0] + bias[ob];
            float v1 = acc[i][j][1] + bias[ob + 1];
            float v2 = acc[i][j][2] + bias[ob + 2];
            float v3 = acc[i][j][3] + bias[ob + 3];
            if (ob < INNER) {                      // Q -> qT[bh][m][c]
                int h = ob >> 6, c = ob & 63;
                f16x4 pk = {(f16)v0, (f16)v1, (f16)v2, (f16)v3};
                *reinterpret_cast<f16x4*>(qT + (((size_t)(b * NH + h) * HW + m) * HD + c)) = pk;
            } else if (ob < 2 * INNER) {           // K -> kT[bh][n][c]
                int oo = ob - INNER;
                int h = oo >> 6, c = oo & 63;
                f16x4 pk = {(f16)v0, (f16)v1, (f16)v2, (f16)v3};
                *reinterpret_cast<f16x4*>(kT + (((size_t)(b * NH + h) * HW + m) * HD + c)) = pk;
            } else {                               // V -> v[bh][c][n]
                int oo = ob - 2 * INNER;
                int h = oo >> 6, c = oo & 63;
                f16* vp = vv + ((size_t)(b * NH + h) * HD + c) * HW + m;
                vp[0]      = (f16)v0;
                vp[HW]     = (f16)v1;
                vp[2 * HW] = (f16)v2;
                vp[3 * HW] = (f16)v3;
            }
        }
    }
}

// ---------------- embedding scale: embS[b][co] = embedding[b,:] . emb_w[co,:] + emb_b ----------------
__global__ void emb_gemm_k(const float* __restrict__ e, const float* __restrict__ ew,
                           const float* __restrict__ eb, float* __restrict__ embS) {
    int b = blockIdx.y;
    int co = blockIdx.x * 4 + (threadIdx.x >> 6);
    int lane = threadIdx.x & 63;
    const float4* ep = reinterpret_cast<const float4*>(e + (size_t)b * TD);
    const float4* wp = reinterpret_cast<const float4*>(ew + (size_t)co * TD);
    float s = 0.f;
    for (int t = lane; t < TD / 4; t += 64) {
        float4 a = ep[t], w = wp[t];
        s += a.x * w.x + a.y * w.y + a.z * w.z + a.w * w.w;
    }
    #pragma unroll
    for (int o = 32; o > 0; o >>= 1) s += __shfl_xor(s, o);
    if (lane == 0) embS[b * NC + co] = s + eb[co];
}

// ---------------- flash attention: per wave 32 query rows, NBLK=32 ----------------
__global__ __launch_bounds__(256) void attn_k(
        const f16* __restrict__ qT, const f16* __restrict__ kT, const f16* __restrict__ vv,
        f16* __restrict__ oT) {
    int bh = blockIdx.x;           // b*NH + h  (x-major so one head's m-tiles share an XCD L2)
    int b = bh >> 3, h = bh & 7;
    int m0 = blockIdx.y * 128;
    int wid = threadIdx.x >> 6;
    int lane = threadIdx.x & 63;
    int lr = lane & 15, lg = lane >> 4;
    int mw = m0 + wid * 32;
    const float scale = 0.125f;    // 1/sqrt(64)

    const f16* qp = qT + (size_t)bh * HW * HD;
    const f16* kp = kT + (size_t)bh * HW * HD;
    const f16* vp = vv + (size_t)bh * HD * HW;

    __shared__ f16 p_lds[4][2][16][32];   // per-wave private P staging

    const f32x4 fzero = {0.f, 0.f, 0.f, 0.f};

    // Q fragments hoisted: A[m][c], rows mw..mw+31, K split c in {0..31, 32..63}
    f16x8 aq[2][2];
    #pragma unroll
    for (int s = 0; s < 2; ++s) {
        #pragma unroll
        for (int kk = 0; kk < 2; ++kk)
            aq[s][kk] = *reinterpret_cast<const f16x8*>(
                qp + (size_t)(mw + s * 16 + lr) * HD + kk * 32 + lg * 8);
    }

    f32x4 oa[2][4];
    float mr[2][4], lsum[2][4];
    #pragma unroll
    for (int s = 0; s < 2; ++s) {
        #pragma unroll
        for (int q = 0; q < 4; ++q) oa[s][q] = fzero;
        #pragma unroll
        for (int r = 0; r < 4; ++r) { mr[s][r] = -1e30f; lsum[s][r] = 0.f; }
    }

    for (int n0 = 0; n0 < HW; n0 += 32) {
        // K fragments: B[c][n], cols n0+j*16+lr, from kT[n][c]
        f16x8 bk[2][2];
        #pragma unroll
        for (int j = 0; j < 2; ++j) {
            #pragma unroll
            for (int kk = 0; kk < 2; ++kk)
                bk[j][kk] = *reinterpret_cast<const f16x8*>(
                    kp + (size_t)(n0 + j * 16 + lr) * HD + kk * 32 + lg * 8);
        }

        #pragma unroll
        for (int s = 0; s < 2; ++s) {
            f32x4 sf0 = fzero, sf1 = fzero;
            sf0 = mfma16(aq[s][0], bk[0][0], sf0);
            sf0 = mfma16(aq[s][1], bk[0][1], sf0);
            sf1 = mfma16(aq[s][0], bk[1][0], sf1);
            sf1 = mfma16(aq[s][1], bk[1][1], sf1);
            // online softmax; D-layout: lane holds rows lg*4+r, col lr (+0/+16)
            #pragma unroll
            for (int r = 0; r < 4; ++r) {
                float v0 = sf0[r] * scale, v1 = sf1[r] * scale;
                float mx = fmaxf(v0, v1);
                #pragma unroll
                for (int o = 1; o < 16; o <<= 1) mx = fmaxf(mx, __shfl_xor(mx, o));
                float mn = fmaxf(mr[s][r], mx);
                float fs = __expf(mr[s][r] - mn);
                mr[s][r] = mn;
                float p0 = __expf(v0 - mn), p1 = __expf(v1 - mn);
                float rsum = p0 + p1;
                #pragma unroll
                for (int o = 1; o < 16; o <<= 1) rsum += __shfl_xor(rsum, o);
                lsum[s][r] = lsum[s][r] * fs + rsum;
                #pragma unroll
                for (int q = 0; q < 4; ++q) oa[s][q][r] *= fs;
                p_lds[wid][s][lg * 4 + r][lr]      = (f16)p0;
                p_lds[wid][s][lg * 4 + r][16 + lr] = (f16)p1;
            }
        }

        // V fragments: B[n][c], from v[c][n]
        f16x8 bv[4];
        #pragma unroll
        for (int q = 0; q < 4; ++q)
            bv[q] = *reinterpret_cast<const f16x8*>(
                vp + (size_t)(q * 16 + lr) * HW + n0 + lg * 8);

        #pragma unroll
        for (int s = 0; s < 2; ++s) {
            f16x8 pa = *reinterpret_cast<const f16x8*>(&p_lds[wid][s][lr][lg * 8]);
            #pragma unroll
            for (int q = 0; q < 4; ++q)
                oa[s][q] = mfma16(pa, bv[q], oa[s][q]);
        }
    }

    // finalize: divide by lsum, store oT[b][m][h*64+c]
    #pragma unroll
    for (int s = 0; s < 2; ++s) {
        float inv[4];
        #pragma unroll
        for (int r = 0; r < 4; ++r) inv[r] = 1.f / lsum[s][r];
        #pragma unroll
        for (int q = 0; q < 4; ++q) {
            #pragma unroll
            for (int r = 0; r < 4; ++r)
                oT[((size_t)b * HW + mw + s * 16 + lg * 4 + r) * INNER + h * HD + q * 16 + lr] =
                    (f16)(oa[s][q][r] * inv[r]);
        }
    }
}

// ---------------- out projection + bias + emb-scale + residual ----------------
__global__ __launch_bounds__(256) void gemm_out_k(
        const f16* __restrict__ wA, const f16* __restrict__ oT,
        const float* __restrict__ bias, const float* __restrict__ embS,
        const float* __restrict__ x, float* __restrict__ out) {
    int b  = blockIdx.z;
    int o0 = blockIdx.x * 128;
    int m0 = blockIdx.y * 128;
    int wid  = threadIdx.x >> 6;
    int lane = threadIdx.x & 63;
    int wr = (wid >> 1) * 64, wc = (wid & 1) * 64;
    int lr = lane & 15, lg = lane >> 4;

    const f16* A  = wA + (size_t)(o0 + wr + lr) * INNER + lg * 8;
    const f16* Bp = oT + ((size_t)b * HW + m0 + wc + lr) * INNER + lg * 8;

    const f32x4 fzero = {0.f, 0.f, 0.f, 0.f};
    f32x4 acc[4][4];
    #pragma unroll
    for (int i = 0; i < 4; ++i) {
        #pragma unroll
        for (int j = 0; j < 4; ++j) acc[i][j] = fzero;
    }

    for (int k0 = 0; k0 < INNER; k0 += 32) {
        f16x8 af[4], bf[4];
        #pragma unroll
        for (int i = 0; i < 4; ++i)
            af[i] = *reinterpret_cast<const f16x8*>(A + (size_t)i * 16 * INNER + k0);
        #pragma unroll
        for (int j = 0; j < 4; ++j)
            bf[j] = *reinterpret_cast<const f16x8*>(Bp + (size_t)j * 16 * INNER + k0);
        #pragma unroll
        for (int i = 0; i < 4; ++i) {
            #pragma unroll
            for (int j = 0; j < 4; ++j)
                acc[i][j] = mfma16(af[i], bf[j], acc[i][j]);
        }
    }

    #pragma unroll
    for (int i = 0; i < 4; ++i) {
        int ob = o0 + wr + i * 16 + lg * 4;
        #pragma unroll
        for (int j = 0; j < 4; ++j) {
            int m = m0 + wc + j * 16 + lr;
            #pragma unroll
            for (int r = 0; r < 4; ++r) {
                int o = ob + r;
                size_t idx = ((size_t)b * NC + o) * HW + m;
                out[idx] = (acc[i][j][r] + bias[o]) * embS[b * NC + o] + x[idx];
            }
        }
    }
}

extern "C" void kernel_launch(void* const* d_in, const int* in_sizes, int n_in,
                              void* d_out, int out_size, void* d_ws, size_t ws_size,
                              hipStream_t stream) {
    const float* x     = (const float*)d_in[0];
    const float* emb   = (const float*)d_in[1];
    const float* nw    = (const float*)d_in[2];
    const float* nbi   = (const float*)d_in[3];
    const float* in_w  = (const float*)d_in[4];
    const float* in_b  = (const float*)d_in[5];
    const float* out_w = (const float*)d_in[6];
    const float* out_b = (const float*)d_in[7];
    const float* emb_w = (const float*)d_in[8];
    const float* emb_b = (const float*)d_in[9];

    char* p = (char*)d_ws;
    f16* xnT   = (f16*)p;   p += (size_t)NB * HW * NC * 2;        // 8 MB
    f16* w_in  = (f16*)p;   p += (size_t)3 * INNER * NC * 2;      // 768 KB
    f16* w_out = (f16*)p;   p += (size_t)NC * INNER * 2;          // 256 KB
    float* stats = (float*)p; p += (size_t)NB * NG * 2 * 4;       // 4 KB
    float* embS  = (float*)p; p += (size_t)NB * NC * 4;           // 16 KB
    f16* qT = (f16*)p;      p += (size_t)NB * NH * HW * HD * 2;   // 16 MB
    f16* kT = (f16*)p;      p += (size_t)NB * NH * HW * HD * 2;   // 16 MB
    f16* vv = (f16*)p;      p += (size_t)NB * NH * HW * HD * 2;   // 16 MB
    f16* oT = (f16*)p;                                            // 16 MB

    gn_stats_k<<<NB * NG, 256, 0, stream>>>(x, stats);
    gn_apply_k<<<dim3(HW / 256, NB), 256, 0, stream>>>(x, stats, nw, nbi, xnT);
    conv_w_k<<<512, 256, 0, stream>>>(in_w, out_w, w_in, w_out);
    gemm_qkv_k<<<dim3(12, 8, NB), 256, 0, stream>>>(w_in, xnT, in_b, qT, kT, vv);
    emb_gemm_k<<<dim3(NC / 4, NB), 256, 0, stream>>>(emb, emb_w, emb_b, embS);
    attn_k<<<dim3(NB * NH, HW / 128), 256, 0, stream>>>(qT, kT, vv, oT);
    gemm_out_k<<<dim3(NC / 128, HW / 128, NB), 256, 0, stream>>>(w_out, oT, out_b, embS, x, (float*)d_out);
}

// Round 5
// 197.241 us; speedup vs baseline: 1.2627x; 1.2627x over previous
//
#include <hip/hip_runtime.h>

#define DEV __device__ __forceinline__

typedef _Float16 f16;
typedef _Float16 f16x8 __attribute__((ext_vector_type(8)));
typedef _Float16 f16x4 __attribute__((ext_vector_type(4)));
typedef float f32x4 __attribute__((ext_vector_type(4)));

static constexpr int NB = 16;       // batch
static constexpr int NC = 256;      // channels
static constexpr int HW = 1024;     // h*w
static constexpr int NG = 32;       // groups
static constexpr int CPG = 8;       // channels per group
static constexpr int NH = 8;        // heads
static constexpr int HD = 64;       // head dim
static constexpr int INNER = 512;   // heads*head_dim
static constexpr int TD = 1024;     // time-embedding dim

DEV f32x4 mfma16(f16x8 a, f16x8 b, f32x4 c) {
    return __builtin_amdgcn_mfma_f32_16x16x32_f16(a, b, c, 0, 0, 0);
}

// ---------------- GroupNorm: per-(b,g) mean/rstd ----------------
__global__ void gn_stats_k(const float* __restrict__ x, float* __restrict__ stats) {
    int bg = blockIdx.x;  // b*NG + g
    const float4* p = reinterpret_cast<const float4*>(x) + (size_t)bg * (CPG * HW / 4);
    float s = 0.f, ss = 0.f;
    for (int i = threadIdx.x; i < CPG * HW / 4; i += 256) {
        float4 v = p[i];
        s  += v.x + v.y + v.z + v.w;
        ss += v.x * v.x + v.y * v.y + v.z * v.z + v.w * v.w;
    }
    #pragma unroll
    for (int o = 32; o > 0; o >>= 1) {
        s  += __shfl_xor(s, o);
        ss += __shfl_xor(ss, o);
    }
    __shared__ float rs[4], rss[4];
    int wid = threadIdx.x >> 6;
    if ((threadIdx.x & 63) == 0) { rs[wid] = s; rss[wid] = ss; }
    __syncthreads();
    if (threadIdx.x == 0) {
        s  = rs[0] + rs[1] + rs[2] + rs[3];
        ss = rss[0] + rss[1] + rss[2] + rss[3];
        const float inv_n = 1.f / (float)(CPG * HW);
        float mean = s * inv_n;
        float var  = ss * inv_n - mean * mean;
        stats[bg * 2]     = mean;
        stats[bg * 2 + 1] = rsqrtf(var + 1e-5f);
    }
}

// ---------------- GroupNorm apply + transpose -> xnT[b][m][c] (f16) ----------------
__global__ void gn_apply_k(const float* __restrict__ x, const float* __restrict__ stats,
                           const float* __restrict__ nw, const float* __restrict__ nb,
                           f16* __restrict__ xnT) {
    int b = blockIdx.y;
    int m = blockIdx.x * 256 + threadIdx.x;
    const float* xb = x + (size_t)b * NC * HW + m;
    f16* op = xnT + ((size_t)b * HW + m) * NC;
    for (int c0 = 0; c0 < NC; c0 += 4) {
        f16x4 h;
        #pragma unroll
        for (int j = 0; j < 4; ++j) {
            int c = c0 + j;
            float mean = stats[(b * NG + (c >> 3)) * 2];
            float rstd = stats[(b * NG + (c >> 3)) * 2 + 1];
            float v = xb[(size_t)c * HW];
            h[j] = (f16)(((v - mean) * rstd) * nw[c] + nb[c]);
        }
        *reinterpret_cast<f16x4*>(op + c0) = h;
    }
}

// ---------------- fp32 -> f16 weight conversion ----------------
__global__ void conv_w_k(const float* __restrict__ a, const float* __restrict__ bw,
                         f16* __restrict__ wa, f16* __restrict__ wb) {
    int i = blockIdx.x * 256 + threadIdx.x;  // float4 index
    const int N1 = 3 * INNER * NC / 4;       // 98304
    float4 v;
    f16* dst;
    if (i < N1) { v = reinterpret_cast<const float4*>(a)[i];      dst = wa + (size_t)i * 4; }
    else        { v = reinterpret_cast<const float4*>(bw)[i - N1]; dst = wb + (size_t)(i - N1) * 4; }
    f16x4 h4 = {(f16)v.x, (f16)v.y, (f16)v.z, (f16)v.w};
    *reinterpret_cast<f16x4*>(dst) = h4;
}

// ---------------- QKV GEMM: qkv[o,m] = in_w[o,:] . xn[b,:,m], scatter to q/k/v ----------------
__global__ __launch_bounds__(256) void gemm_qkv_k(
        const f16* __restrict__ wA, const f16* __restrict__ xnT,
        const float* __restrict__ bias,
        f16* __restrict__ qT, f16* __restrict__ kT, f16* __restrict__ vv) {
    int b  = blockIdx.z;
    int o0 = blockIdx.x * 128;
    int m0 = blockIdx.y * 128;
    int wid  = threadIdx.x >> 6;
    int lane = threadIdx.x & 63;
    int wr = (wid >> 1) * 64, wc = (wid & 1) * 64;
    int lr = lane & 15, lg = lane >> 4;

    const f16* A  = wA  + (size_t)(o0 + wr + lr) * NC + lg * 8;
    const f16* Bp = xnT + ((size_t)b * HW + m0 + wc + lr) * NC + lg * 8;

    const f32x4 fzero = {0.f, 0.f, 0.f, 0.f};
    f32x4 acc[4][4];
    #pragma unroll
    for (int i = 0; i < 4; ++i) {
        #pragma unroll
        for (int j = 0; j < 4; ++j) acc[i][j] = fzero;
    }

    for (int k0 = 0; k0 < NC; k0 += 32) {
        f16x8 af[4], bf[4];
        #pragma unroll
        for (int i = 0; i < 4; ++i)
            af[i] = *reinterpret_cast<const f16x8*>(A + (size_t)i * 16 * NC + k0);
        #pragma unroll
        for (int j = 0; j < 4; ++j)
            bf[j] = *reinterpret_cast<const f16x8*>(Bp + (size_t)j * 16 * NC + k0);
        #pragma unroll
        for (int i = 0; i < 4; ++i) {
            #pragma unroll
            for (int j = 0; j < 4; ++j)
                acc[i][j] = mfma16(af[i], bf[j], acc[i][j]);
        }
    }

    #pragma unroll
    for (int i = 0; i < 4; ++i) {
        int ob = o0 + wr + i * 16 + lg * 4;  // first of 4 consecutive output rows
        #pragma unroll
        for (int j = 0; j < 4; ++j) {
            int m = m0 + wc + j * 16 + lr;
            float v0 = acc[i][j][0] + bias[ob];
            float v1 = acc[i][j][1] + bias[ob + 1];
            float v2 = acc[i][j][2] + bias[ob + 2];
            float v3 = acc[i][j][3] + bias[ob + 3];
            if (ob < INNER) {                      // Q -> qT[bh][m][c]
                int h = ob >> 6, c = ob & 63;
                f16x4 pk = {(f16)v0, (f16)v1, (f16)v2, (f16)v3};
                *reinterpret_cast<f16x4*>(qT + (((size_t)(b * NH + h) * HW + m) * HD + c)) = pk;
            } else if (ob < 2 * INNER) {           // K -> kT[bh][n][c]
                int oo = ob - INNER;
                int h = oo >> 6, c = oo & 63;
                f16x4 pk = {(f16)v0, (f16)v1, (f16)v2, (f16)v3};
                *reinterpret_cast<f16x4*>(kT + (((size_t)(b * NH + h) * HW + m) * HD + c)) = pk;
            } else {                               // V -> v[bh][c][n]
                int oo = ob - 2 * INNER;
                int h = oo >> 6, c = oo & 63;
                f16* vp = vv + ((size_t)(b * NH + h) * HD + c) * HW + m;
                vp[0]      = (f16)v0;
                vp[HW]     = (f16)v1;
                vp[2 * HW] = (f16)v2;
                vp[3 * HW] = (f16)v3;
            }
        }
    }
}

// ---------------- embedding scale: embS[b][co] = embedding[b,:] . emb_w[co,:] + emb_b ----------------
__global__ void emb_gemm_k(const float* __restrict__ e, const float* __restrict__ ew,
                           const float* __restrict__ eb, float* __restrict__ embS) {
    int b = blockIdx.y;
    int co = blockIdx.x * 4 + (threadIdx.x >> 6);
    int lane = threadIdx.x & 63;
    const float4* ep = reinterpret_cast<const float4*>(e + (size_t)b * TD);
    const float4* wp = reinterpret_cast<const float4*>(ew + (size_t)co * TD);
    float s = 0.f;
    for (int t = lane; t < TD / 4; t += 64) {
        float4 a = ep[t], w = wp[t];
        s += a.x * w.x + a.y * w.y + a.z * w.z + a.w * w.w;
    }
    #pragma unroll
    for (int o = 32; o > 0; o >>= 1) s += __shfl_xor(s, o);
    if (lane == 0) embS[b * NC + co] = s + eb[co];
}

// ---------------- flash attention: swapped S^T, 16x16 MFMAs ONLY ----------------
// Every MFMA operand/output map here is the round-1 hardware-verified 16x16x32
// pattern: A[l&15][(l>>4)*8+j], B[(l>>4)*8+j][l&15], D row=(l>>4)*4+r col=l&15.
// Per wave: 64 queries (4 subtiles of 16), 32-key tiles.
// S^T = mfma16(A=K, B=Q): lane (lr,lg) holds scores for query lr (col) at
// keys kt*16 + lg*4 + r. Row-reduce = in-lane tree + shfl_xor(16,32).
// P relayed via per-wave LDS [q][key] (write C/D formula, read one f16x8
// B-fragment). PV = mfma16(A=V^T, B=P), O^T store via C/D formula.
__global__ __launch_bounds__(256) void attn_k(
        const f16* __restrict__ qT, const f16* __restrict__ kT, const f16* __restrict__ vv,
        f16* __restrict__ oT) {
    int bh = blockIdx.x;           // b*NH + h
    int b = bh >> 3, h = bh & 7;
    int wid = threadIdx.x >> 6;
    int lane = threadIdx.x & 63;
    int lr = lane & 15, lg = lane >> 4;
    int mw = blockIdx.y * 256 + wid * 64;

    const f16* qp = qT + (size_t)bh * HW * HD;
    const f16* kp = kT + (size_t)bh * HW * HD;
    const f16* vp = vv + (size_t)bh * HD * HW;

    const float sl = 0.125f * 1.44269504088896f;  // scale * log2(e)

    // per-wave P tile [q=16][key=32 padded to 40] (rows 80B -> 16B-aligned)
    __shared__ __align__(16) f16 pl[4][16][40];

    // Q fragments (B-operand): col=q=lr, k = d = ks2*32 + lg*8 + j
    f16x8 qf[4][2];
    #pragma unroll
    for (int qt = 0; qt < 4; ++qt)
        #pragma unroll
        for (int ks2 = 0; ks2 < 2; ++ks2)
            qf[qt][ks2] = *reinterpret_cast<const f16x8*>(
                qp + (size_t)(mw + qt * 16 + lr) * HD + ks2 * 32 + lg * 8);

    const f32x4 fzero = {0.f, 0.f, 0.f, 0.f};
    f32x4 oa[4][4];                // [qt][dt] : O^T[d=dt*16+lg*4+r][q=qt*16+lr]
    #pragma unroll
    for (int qt = 0; qt < 4; ++qt)
        #pragma unroll
        for (int dt = 0; dt < 4; ++dt) oa[qt][dt] = fzero;
    float mr[4] = {-1e30f, -1e30f, -1e30f, -1e30f};
    float ls[4] = {0.f, 0.f, 0.f, 0.f};

    for (int n0 = 0; n0 < HW; n0 += 32) {
        // K fragments (A-operand): row = key = kt*16+lr, k = d-slice
        f16x8 kf[2][2];
        #pragma unroll
        for (int kt = 0; kt < 2; ++kt)
            #pragma unroll
            for (int ks2 = 0; ks2 < 2; ++ks2)
                kf[kt][ks2] = *reinterpret_cast<const f16x8*>(
                    kp + (size_t)(n0 + kt * 16 + lr) * HD + ks2 * 32 + lg * 8);
        // V fragments (A-operand): row = d = dt*16+lr, k = key = lg*8+j
        f16x8 vf[4];
        #pragma unroll
        for (int dt = 0; dt < 4; ++dt)
            vf[dt] = *reinterpret_cast<const f16x8*>(
                vp + (size_t)(dt * 16 + lr) * HW + n0 + lg * 8);

        #pragma unroll
        for (int qt = 0; qt < 4; ++qt) {
            // S^T[key][q] for this query subtile
            f32x4 sc[2] = {fzero, fzero};
            __builtin_amdgcn_s_setprio(1);
            #pragma unroll
            for (int kt = 0; kt < 2; ++kt)
                #pragma unroll
                for (int ks2 = 0; ks2 < 2; ++ks2)
                    sc[kt] = mfma16(kf[kt][ks2], qf[qt][ks2], sc[kt]);
            __builtin_amdgcn_s_setprio(0);

            // softmax: lane holds 8 of the 32 key-scores for query lr
            float a0 = fmaxf(fmaxf(sc[0][0], sc[0][1]), fmaxf(sc[0][2], sc[0][3]));
            float a1 = fmaxf(fmaxf(sc[1][0], sc[1][1]), fmaxf(sc[1][2], sc[1][3]));
            float pm = fmaxf(a0, a1) * sl;
            pm = fmaxf(pm, __shfl_xor(pm, 16));
            pm = fmaxf(pm, __shfl_xor(pm, 32));
            float mn = fmaxf(mr[qt], pm);
            float f = exp2f(mr[qt] - mn);       // first tile: exp2(-huge)=0
            mr[qt] = mn;
            ls[qt] *= f;
            #pragma unroll
            for (int dt = 0; dt < 4; ++dt) {
                #pragma unroll
                for (int r = 0; r < 4; ++r) oa[qt][dt][r] *= f;
            }
            float p[8];
            #pragma unroll
            for (int kt = 0; kt < 2; ++kt)
                #pragma unroll
                for (int r = 0; r < 4; ++r)
                    p[kt * 4 + r] = exp2f(fmaf(sc[kt][r], sl, -mn));
            float rsum = ((p[0] + p[1]) + (p[2] + p[3])) + ((p[4] + p[5]) + (p[6] + p[7]));
            rsum += __shfl_xor(rsum, 16);
            rsum += __shfl_xor(rsum, 32);
            ls[qt] += rsum;

            // relay P via LDS: row q=lr, key = kt*16 + lg*4 + r (C/D formula)
            f16x4 w0 = {(f16)p[0], (f16)p[1], (f16)p[2], (f16)p[3]};
            f16x4 w1 = {(f16)p[4], (f16)p[5], (f16)p[6], (f16)p[7]};
            *reinterpret_cast<f16x4*>(&pl[wid][lr][lg * 4])      = w0;
            *reinterpret_cast<f16x4*>(&pl[wid][lr][16 + lg * 4]) = w1;
            // read B-fragment: B[k=key=lg*8+j][col=q=lr] (one 16B read)
            f16x8 pf = *reinterpret_cast<const f16x8*>(&pl[wid][lr][lg * 8]);

            // PV: O^T[d][q] += V^T . P^T
            __builtin_amdgcn_s_setprio(1);
            #pragma unroll
            for (int dt = 0; dt < 4; ++dt)
                oa[qt][dt] = mfma16(vf[dt], pf, oa[qt][dt]);
            __builtin_amdgcn_s_setprio(0);
        }
    }

    // store: O^T row = d = dt*16 + lg*4 + r, col = q = qt*16 + lr
    #pragma unroll
    for (int qt = 0; qt < 4; ++qt) {
        float inv = 1.f / ls[qt];
        int m = mw + qt * 16 + lr;
        f16* op = oT + ((size_t)b * HW + m) * INNER + h * HD;
        #pragma unroll
        for (int dt = 0; dt < 4; ++dt) {
            f16x4 o4;
            #pragma unroll
            for (int r = 0; r < 4; ++r) o4[r] = (f16)(oa[qt][dt][r] * inv);
            *reinterpret_cast<f16x4*>(op + dt * 16 + lg * 4) = o4;
        }
    }
}

// ---------------- out projection + bias + emb-scale + residual ----------------
__global__ __launch_bounds__(256) void gemm_out_k(
        const f16* __restrict__ wA, const f16* __restrict__ oT,
        const float* __restrict__ bias, const float* __restrict__ embS,
        const float* __restrict__ x, float* __restrict__ out) {
    int b  = blockIdx.z;
    int o0 = blockIdx.x * 128;
    int m0 = blockIdx.y * 128;
    int wid  = threadIdx.x >> 6;
    int lane = threadIdx.x & 63;
    int wr = (wid >> 1) * 64, wc = (wid & 1) * 64;
    int lr = lane & 15, lg = lane >> 4;

    const f16* A  = wA + (size_t)(o0 + wr + lr) * INNER + lg * 8;
    const f16* Bp = oT + ((size_t)b * HW + m0 + wc + lr) * INNER + lg * 8;

    const f32x4 fzero = {0.f, 0.f, 0.f, 0.f};
    f32x4 acc[4][4];
    #pragma unroll
    for (int i = 0; i < 4; ++i) {
        #pragma unroll
        for (int j = 0; j < 4; ++j) acc[i][j] = fzero;
    }

    for (int k0 = 0; k0 < INNER; k0 += 32) {
        f16x8 af[4], bf[4];
        #pragma unroll
        for (int i = 0; i < 4; ++i)
            af[i] = *reinterpret_cast<const f16x8*>(A + (size_t)i * 16 * INNER + k0);
        #pragma unroll
        for (int j = 0; j < 4; ++j)
            bf[j] = *reinterpret_cast<const f16x8*>(Bp + (size_t)j * 16 * INNER + k0);
        #pragma unroll
        for (int i = 0; i < 4; ++i) {
            #pragma unroll
            for (int j = 0; j < 4; ++j)
                acc[i][j] = mfma16(af[i], bf[j], acc[i][j]);
        }
    }

    #pragma unroll
    for (int i = 0; i < 4; ++i) {
        int ob = o0 + wr + i * 16 + lg * 4;
        #pragma unroll
        for (int j = 0; j < 4; ++j) {
            int m = m0 + wc + j * 16 + lr;
            #pragma unroll
            for (int r = 0; r < 4; ++r) {
                int o = ob + r;
                size_t idx = ((size_t)b * NC + o) * HW + m;
                out[idx] = (acc[i][j][r] + bias[o]) * embS[b * NC + o] + x[idx];
            }
        }
    }
}

extern "C" void kernel_launch(void* const* d_in, const int* in_sizes, int n_in,
                              void* d_out, int out_size, void* d_ws, size_t ws_size,
                              hipStream_t stream) {
    const float* x     = (const float*)d_in[0];
    const float* emb   = (const float*)d_in[1];
    const float* nw    = (const float*)d_in[2];
    const float* nbi   = (const float*)d_in[3];
    const float* in_w  = (const float*)d_in[4];
    const float* in_b  = (const float*)d_in[5];
    const float* out_w = (const float*)d_in[6];
    const float* out_b = (const float*)d_in[7];
    const float* emb_w = (const float*)d_in[8];
    const float* emb_b = (const float*)d_in[9];

    char* p = (char*)d_ws;
    f16* xnT   = (f16*)p;   p += (size_t)NB * HW * NC * 2;        // 8 MB
    f16* w_in  = (f16*)p;   p += (size_t)3 * INNER * NC * 2;      // 768 KB
    f16* w_out = (f16*)p;   p += (size_t)NC * INNER * 2;          // 256 KB
    float* stats = (float*)p; p += (size_t)NB * NG * 2 * 4;       // 4 KB
    float* embS  = (float*)p; p += (size_t)NB * NC * 4;           // 16 KB
    f16* qT = (f16*)p;      p += (size_t)NB * NH * HW * HD * 2;   // 16 MB
    f16* kT = (f16*)p;      p += (size_t)NB * NH * HW * HD * 2;   // 16 MB
    f16* vv = (f16*)p;      p += (size_t)NB * NH * HW * HD * 2;   // 16 MB
    f16* oT = (f16*)p;                                            // 16 MB

    gn_stats_k<<<NB * NG, 256, 0, stream>>>(x, stats);
    gn_apply_k<<<dim3(HW / 256, NB), 256, 0, stream>>>(x, stats, nw, nbi, xnT);
    conv_w_k<<<512, 256, 0, stream>>>(in_w, out_w, w_in, w_out);
    gemm_qkv_k<<<dim3(12, 8, NB), 256, 0, stream>>>(w_in, xnT, in_b, qT, kT, vv);
    emb_gemm_k<<<dim3(NC / 4, NB), 256, 0, stream>>>(emb, emb_w, emb_b, embS);
    attn_k<<<dim3(NB * NH, HW / 256), 256, 0, stream>>>(qT, kT, vv, oT);
    gemm_out_k<<<dim3(NC / 128, HW / 128, NB), 256, 0, stream>>>(w_out, oT, out_b, embS, x, (float*)d_out);
}

// Round 6
// 178.407 us; speedup vs baseline: 1.3960x; 1.1056x over previous
//
#include <hip/hip_runtime.h>

#define DEV __device__ __forceinline__

typedef _Float16 f16;
typedef _Float16 f16x8 __attribute__((ext_vector_type(8)));
typedef _Float16 f16x4 __attribute__((ext_vector_type(4)));
typedef float f32x4 __attribute__((ext_vector_type(4)));

static constexpr int NB = 16;       // batch
static constexpr int NC = 256;      // channels
static constexpr int HW = 1024;     // h*w
static constexpr int NG = 32;       // groups
static constexpr int CPG = 8;       // channels per group
static constexpr int NH = 8;        // heads
static constexpr int HD = 64;       // head dim
static constexpr int INNER = 512;   // heads*head_dim
static constexpr int TD = 1024;     // time-embedding dim

DEV f32x4 mfma16(f16x8 a, f16x8 b, f32x4 c) {
    return __builtin_amdgcn_mfma_f32_16x16x32_f16(a, b, c, 0, 0, 0);
}

// ---------------- GroupNorm: per-(b,g) mean/rstd ----------------
__global__ void gn_stats_k(const float* __restrict__ x, float* __restrict__ stats) {
    int bg = blockIdx.x;  // b*NG + g
    const float4* p = reinterpret_cast<const float4*>(x) + (size_t)bg * (CPG * HW / 4);
    float s = 0.f, ss = 0.f;
    for (int i = threadIdx.x; i < CPG * HW / 4; i += 256) {
        float4 v = p[i];
        s  += v.x + v.y + v.z + v.w;
        ss += v.x * v.x + v.y * v.y + v.z * v.z + v.w * v.w;
    }
    #pragma unroll
    for (int o = 32; o > 0; o >>= 1) {
        s  += __shfl_xor(s, o);
        ss += __shfl_xor(ss, o);
    }
    __shared__ float rs[4], rss[4];
    int wid = threadIdx.x >> 6;
    if ((threadIdx.x & 63) == 0) { rs[wid] = s; rss[wid] = ss; }
    __syncthreads();
    if (threadIdx.x == 0) {
        s  = rs[0] + rs[1] + rs[2] + rs[3];
        ss = rss[0] + rss[1] + rss[2] + rss[3];
        const float inv_n = 1.f / (float)(CPG * HW);
        float mean = s * inv_n;
        float var  = ss * inv_n - mean * mean;
        stats[bg * 2]     = mean;
        stats[bg * 2 + 1] = rsqrtf(var + 1e-5f);
    }
}

// ---------------- GroupNorm apply + transpose -> xnT[b][m][c] (f16) ----------------
__global__ void gn_apply_k(const float* __restrict__ x, const float* __restrict__ stats,
                           const float* __restrict__ nw, const float* __restrict__ nb,
                           f16* __restrict__ xnT) {
    int b = blockIdx.y;
    int m = blockIdx.x * 256 + threadIdx.x;
    const float* xb = x + (size_t)b * NC * HW + m;
    f16* op = xnT + ((size_t)b * HW + m) * NC;
    for (int c0 = 0; c0 < NC; c0 += 4) {
        f16x4 h;
        #pragma unroll
        for (int j = 0; j < 4; ++j) {
            int c = c0 + j;
            float mean = stats[(b * NG + (c >> 3)) * 2];
            float rstd = stats[(b * NG + (c >> 3)) * 2 + 1];
            float v = xb[(size_t)c * HW];
            h[j] = (f16)(((v - mean) * rstd) * nw[c] + nb[c]);
        }
        *reinterpret_cast<f16x4*>(op + c0) = h;
    }
}

// ---------------- fp32 -> f16 weight conversion ----------------
__global__ void conv_w_k(const float* __restrict__ a, const float* __restrict__ bw,
                         f16* __restrict__ wa, f16* __restrict__ wb) {
    int i = blockIdx.x * 256 + threadIdx.x;  // float4 index
    const int N1 = 3 * INNER * NC / 4;       // 98304
    float4 v;
    f16* dst;
    if (i < N1) { v = reinterpret_cast<const float4*>(a)[i];      dst = wa + (size_t)i * 4; }
    else        { v = reinterpret_cast<const float4*>(bw)[i - N1]; dst = wb + (size_t)(i - N1) * 4; }
    f16x4 h4 = {(f16)v.x, (f16)v.y, (f16)v.z, (f16)v.w};
    *reinterpret_cast<f16x4*>(dst) = h4;
}

// ---------------- QKV GEMM: qkv[o,m] = in_w[o,:] . xn[b,:,m], scatter to q/k/v ----------------
__global__ __launch_bounds__(256) void gemm_qkv_k(
        const f16* __restrict__ wA, const f16* __restrict__ xnT,
        const float* __restrict__ bias,
        f16* __restrict__ qT, f16* __restrict__ kT, f16* __restrict__ vv) {
    int b  = blockIdx.z;
    int o0 = blockIdx.x * 128;
    int m0 = blockIdx.y * 128;
    int wid  = threadIdx.x >> 6;
    int lane = threadIdx.x & 63;
    int wr = (wid >> 1) * 64, wc = (wid & 1) * 64;
    int lr = lane & 15, lg = lane >> 4;

    const f16* A  = wA  + (size_t)(o0 + wr + lr) * NC + lg * 8;
    const f16* Bp = xnT + ((size_t)b * HW + m0 + wc + lr) * NC + lg * 8;

    const f32x4 fzero = {0.f, 0.f, 0.f, 0.f};
    f32x4 acc[4][4];
    #pragma unroll
    for (int i = 0; i < 4; ++i) {
        #pragma unroll
        for (int j = 0; j < 4; ++j) acc[i][j] = fzero;
    }

    for (int k0 = 0; k0 < NC; k0 += 32) {
        f16x8 af[4], bf[4];
        #pragma unroll
        for (int i = 0; i < 4; ++i)
            af[i] = *reinterpret_cast<const f16x8*>(A + (size_t)i * 16 * NC + k0);
        #pragma unroll
        for (int j = 0; j < 4; ++j)
            bf[j] = *reinterpret_cast<const f16x8*>(Bp + (size_t)j * 16 * NC + k0);
        #pragma unroll
        for (int i = 0; i < 4; ++i) {
            #pragma unroll
            for (int j = 0; j < 4; ++j)
                acc[i][j] = mfma16(af[i], bf[j], acc[i][j]);
        }
    }

    #pragma unroll
    for (int i = 0; i < 4; ++i) {
        int ob = o0 + wr + i * 16 + lg * 4;  // first of 4 consecutive output rows
        #pragma unroll
        for (int j = 0; j < 4; ++j) {
            int m = m0 + wc + j * 16 + lr;
            float v0 = acc[i][j][0] + bias[ob];
            float v1 = acc[i][j][1] + bias[ob + 1];
            float v2 = acc[i][j][2] + bias[ob + 2];
            float v3 = acc[i][j][3] + bias[ob + 3];
            if (ob < INNER) {                      // Q -> qT[bh][m][c]
                int h = ob >> 6, c = ob & 63;
                f16x4 pk = {(f16)v0, (f16)v1, (f16)v2, (f16)v3};
                *reinterpret_cast<f16x4*>(qT + (((size_t)(b * NH + h) * HW + m) * HD + c)) = pk;
            } else if (ob < 2 * INNER) {           // K -> kT[bh][n][c]
                int oo = ob - INNER;
                int h = oo >> 6, c = oo & 63;
                f16x4 pk = {(f16)v0, (f16)v1, (f16)v2, (f16)v3};
                *reinterpret_cast<f16x4*>(kT + (((size_t)(b * NH + h) * HW + m) * HD + c)) = pk;
            } else {                               // V -> v[bh][c][n]
                int oo = ob - 2 * INNER;
                int h = oo >> 6, c = oo & 63;
                f16* vp = vv + ((size_t)(b * NH + h) * HD + c) * HW + m;
                vp[0]      = (f16)v0;
                vp[HW]     = (f16)v1;
                vp[2 * HW] = (f16)v2;
                vp[3 * HW] = (f16)v3;
            }
        }
    }
}

// ---------------- embedding scale: embS[b][co] = embedding[b,:] . emb_w[co,:] + emb_b ----------------
__global__ void emb_gemm_k(const float* __restrict__ e, const float* __restrict__ ew,
                           const float* __restrict__ eb, float* __restrict__ embS) {
    int b = blockIdx.y;
    int co = blockIdx.x * 4 + (threadIdx.x >> 6);
    int lane = threadIdx.x & 63;
    const float4* ep = reinterpret_cast<const float4*>(e + (size_t)b * TD);
    const float4* wp = reinterpret_cast<const float4*>(ew + (size_t)co * TD);
    float s = 0.f;
    for (int t = lane; t < TD / 4; t += 64) {
        float4 a = ep[t], w = wp[t];
        s += a.x * w.x + a.y * w.y + a.z * w.z + a.w * w.w;
    }
    #pragma unroll
    for (int o = 32; o > 0; o >>= 1) s += __shfl_xor(s, o);
    if (lane == 0) embS[b * NC + co] = s + eb[co];
}

// ---------------- flash attention helpers ----------------
DEV void load_kv(const f16* __restrict__ kp, const f16* __restrict__ vp,
                 int n0, int lr, int lg, f16x8 (&kf)[2][2], f16x8 (&vf)[4]) {
    #pragma unroll
    for (int kt = 0; kt < 2; ++kt)
        #pragma unroll
        for (int ks2 = 0; ks2 < 2; ++ks2)
            kf[kt][ks2] = *reinterpret_cast<const f16x8*>(
                kp + (size_t)(n0 + kt * 16 + lr) * HD + ks2 * 32 + lg * 8);
    #pragma unroll
    for (int dt = 0; dt < 4; ++dt)
        vf[dt] = *reinterpret_cast<const f16x8*>(
            vp + (size_t)(dt * 16 + lr) * HW + n0 + lg * 8);
}

// One 32-key tile, all round-1-verified 16x16x32 maps.
// Common path: zero shuffles, zero O-rescale (defer-max, per-lane partial ls).
DEV void attn_tile(const f16x8 (&kf)[2][2], const f16x8 (&vf)[4],
                   const f16x8 (&qf)[4][2],
                   f32x4 (&oa)[4][4], float (&mr)[4], float (&lsl)[4],
                   f16 (&pl)[16][40], int lr, int lg) {
    const float sl = 0.125f * 1.44269504088896f;  // scale * log2(e)
    const float THR = 11.0f;                       // p <= 2^11, f16-safe
    const f32x4 fzero = {0.f, 0.f, 0.f, 0.f};
    #pragma unroll
    for (int qt = 0; qt < 4; ++qt) {
        f32x4 sc0 = fzero, sc1 = fzero;
        __builtin_amdgcn_s_setprio(1);
        sc0 = mfma16(kf[0][0], qf[qt][0], sc0);
        sc0 = mfma16(kf[0][1], qf[qt][1], sc0);
        sc1 = mfma16(kf[1][0], qf[qt][0], sc1);
        sc1 = mfma16(kf[1][1], qf[qt][1], sc1);
        __builtin_amdgcn_s_setprio(0);

        // lane (lr,lg) holds scores for query lr at keys {kt*16 + lg*4 + r}
        float a0 = fmaxf(fmaxf(sc0[0], sc0[1]), fmaxf(sc0[2], sc0[3]));
        float a1 = fmaxf(fmaxf(sc1[0], sc1[1]), fmaxf(sc1[2], sc1[3]));
        float pmax = fmaxf(a0, a1) * sl;
        if (__any(pmax - mr[qt] > THR)) {   // rare: true ~once per wave
            float pm = pmax;
            pm = fmaxf(pm, __shfl_xor(pm, 16));
            pm = fmaxf(pm, __shfl_xor(pm, 32));
            float mn = fmaxf(mr[qt], pm);
            float f = exp2f(mr[qt] - mn);   // first tile: exp2(-huge) = 0
            mr[qt] = mn;
            lsl[qt] *= f;
            #pragma unroll
            for (int dt = 0; dt < 4; ++dt)
                #pragma unroll
                for (int r = 0; r < 4; ++r) oa[qt][dt][r] *= f;
        }
        float p[8];
        #pragma unroll
        for (int r = 0; r < 4; ++r) p[r]     = exp2f(fmaf(sc0[r], sl, -mr[qt]));
        #pragma unroll
        for (int r = 0; r < 4; ++r) p[4 + r] = exp2f(fmaf(sc1[r], sl, -mr[qt]));
        lsl[qt] += ((p[0] + p[1]) + (p[2] + p[3])) + ((p[4] + p[5]) + (p[6] + p[7]));

        // relay P via per-wave LDS (write C/D formula, read one B-fragment)
        f16x4 w0 = {(f16)p[0], (f16)p[1], (f16)p[2], (f16)p[3]};
        f16x4 w1 = {(f16)p[4], (f16)p[5], (f16)p[6], (f16)p[7]};
        *reinterpret_cast<f16x4*>(&pl[lr][lg * 4])      = w0;
        *reinterpret_cast<f16x4*>(&pl[lr][16 + lg * 4]) = w1;
        f16x8 pf = *reinterpret_cast<const f16x8*>(&pl[lr][lg * 8]);

        __builtin_amdgcn_s_setprio(1);
        #pragma unroll
        for (int dt = 0; dt < 4; ++dt)
            oa[qt][dt] = mfma16(vf[dt], pf, oa[qt][dt]);
        __builtin_amdgcn_s_setprio(0);
    }
}

// ---------------- flash attention: swapped S^T, 16x16 MFMAs, prefetched K/V ----------------
__global__ __launch_bounds__(256) void attn_k(
        const f16* __restrict__ qT, const f16* __restrict__ kT, const f16* __restrict__ vv,
        f16* __restrict__ oT) {
    // XCD swizzle: 512 blocks, bid%8 -> XCD; give each XCD 16 whole bh's
    int u = ((blockIdx.x & 7) << 6) | (blockIdx.x >> 3);
    int bh = u >> 2;               // b*NH + h
    int mt = u & 3;
    int b = bh >> 3, h = bh & 7;
    int wid = threadIdx.x >> 6;
    int lane = threadIdx.x & 63;
    int lr = lane & 15, lg = lane >> 4;
    int mw = mt * 256 + wid * 64;

    const f16* qp = qT + (size_t)bh * HW * HD;
    const f16* kp = kT + (size_t)bh * HW * HD;
    const f16* vp = vv + (size_t)bh * HD * HW;

    // per-wave P tile [q=16][key=32 padded to 40]
    __shared__ __align__(16) f16 pl[4][16][40];

    // Q fragments (B-operand): col=q=lr, k = d = ks2*32 + lg*8 + j
    f16x8 qf[4][2];
    #pragma unroll
    for (int qt = 0; qt < 4; ++qt)
        #pragma unroll
        for (int ks2 = 0; ks2 < 2; ++ks2)
            qf[qt][ks2] = *reinterpret_cast<const f16x8*>(
                qp + (size_t)(mw + qt * 16 + lr) * HD + ks2 * 32 + lg * 8);

    const f32x4 fzero = {0.f, 0.f, 0.f, 0.f};
    f32x4 oa[4][4];                // [qt][dt] : O^T[d=dt*16+lg*4+r][q=qt*16+lr]
    #pragma unroll
    for (int qt = 0; qt < 4; ++qt)
        #pragma unroll
        for (int dt = 0; dt < 4; ++dt) oa[qt][dt] = fzero;
    float mr[4]  = {-1e30f, -1e30f, -1e30f, -1e30f};
    float lsl[4] = {0.f, 0.f, 0.f, 0.f};   // per-lane partial denominators

    // K/V register double-buffer: compute A while B loads, and vice versa
    f16x8 kfA[2][2], vfA[4], kfB[2][2], vfB[4];
    load_kv(kp, vp, 0, lr, lg, kfA, vfA);
    for (int n0 = 0; n0 < HW; n0 += 64) {
        load_kv(kp, vp, n0 + 32, lr, lg, kfB, vfB);
        attn_tile(kfA, vfA, qf, oa, mr, lsl, pl[wid], lr, lg);
        if (n0 + 64 < HW) load_kv(kp, vp, n0 + 64, lr, lg, kfA, vfA);
        attn_tile(kfB, vfB, qf, oa, mr, lsl, pl[wid], lr, lg);
    }

    // finalize: reduce per-lane partials across the 4 lg lanes per query
    #pragma unroll
    for (int qt = 0; qt < 4; ++qt) {
        float t = lsl[qt];
        t += __shfl_xor(t, 16);
        t += __shfl_xor(t, 32);
        float inv = 1.f / t;
        int m = mw + qt * 16 + lr;
        f16* op = oT + ((size_t)b * HW + m) * INNER + h * HD;
        #pragma unroll
        for (int dt = 0; dt < 4; ++dt) {
            f16x4 o4;
            #pragma unroll
            for (int r = 0; r < 4; ++r) o4[r] = (f16)(oa[qt][dt][r] * inv);
            *reinterpret_cast<f16x4*>(op + dt * 16 + lg * 4) = o4;
        }
    }
}

// ---------------- out projection + bias + emb-scale + residual ----------------
__global__ __launch_bounds__(256) void gemm_out_k(
        const f16* __restrict__ wA, const f16* __restrict__ oT,
        const float* __restrict__ bias, const float* __restrict__ embS,
        const float* __restrict__ x, float* __restrict__ out) {
    int b  = blockIdx.z;
    int o0 = blockIdx.x * 128;
    int m0 = blockIdx.y * 128;
    int wid  = threadIdx.x >> 6;
    int lane = threadIdx.x & 63;
    int wr = (wid >> 1) * 64, wc = (wid & 1) * 64;
    int lr = lane & 15, lg = lane >> 4;

    const f16* A  = wA + (size_t)(o0 + wr + lr) * INNER + lg * 8;
    const f16* Bp = oT + ((size_t)b * HW + m0 + wc + lr) * INNER + lg * 8;

    const f32x4 fzero = {0.f, 0.f, 0.f, 0.f};
    f32x4 acc[4][4];
    #pragma unroll
    for (int i = 0; i < 4; ++i) {
        #pragma unroll
        for (int j = 0; j < 4; ++j) acc[i][j] = fzero;
    }

    for (int k0 = 0; k0 < INNER; k0 += 32) {
        f16x8 af[4], bf[4];
        #pragma unroll
        for (int i = 0; i < 4; ++i)
            af[i] = *reinterpret_cast<const f16x8*>(A + (size_t)i * 16 * INNER + k0);
        #pragma unroll
        for (int j = 0; j < 4; ++j)
            bf[j] = *reinterpret_cast<const f16x8*>(Bp + (size_t)j * 16 * INNER + k0);
        #pragma unroll
        for (int i = 0; i < 4; ++i) {
            #pragma unroll
            for (int j = 0; j < 4; ++j)
                acc[i][j] = mfma16(af[i], bf[j], acc[i][j]);
        }
    }

    #pragma unroll
    for (int i = 0; i < 4; ++i) {
        int ob = o0 + wr + i * 16 + lg * 4;
        #pragma unroll
        for (int j = 0; j < 4; ++j) {
            int m = m0 + wc + j * 16 + lr;
            #pragma unroll
            for (int r = 0; r < 4; ++r) {
                int o = ob + r;
                size_t idx = ((size_t)b * NC + o) * HW + m;
                out[idx] = (acc[i][j][r] + bias[o]) * embS[b * NC + o] + x[idx];
            }
        }
    }
}

extern "C" void kernel_launch(void* const* d_in, const int* in_sizes, int n_in,
                              void* d_out, int out_size, void* d_ws, size_t ws_size,
                              hipStream_t stream) {
    const float* x     = (const float*)d_in[0];
    const float* emb   = (const float*)d_in[1];
    const float* nw    = (const float*)d_in[2];
    const float* nbi   = (const float*)d_in[3];
    const float* in_w  = (const float*)d_in[4];
    const float* in_b  = (const float*)d_in[5];
    const float* out_w = (const float*)d_in[6];
    const float* out_b = (const float*)d_in[7];
    const float* emb_w = (const float*)d_in[8];
    const float* emb_b = (const float*)d_in[9];

    char* p = (char*)d_ws;
    f16* xnT   = (f16*)p;   p += (size_t)NB * HW * NC * 2;        // 8 MB
    f16* w_in  = (f16*)p;   p += (size_t)3 * INNER * NC * 2;      // 768 KB
    f16* w_out = (f16*)p;   p += (size_t)NC * INNER * 2;          // 256 KB
    float* stats = (float*)p; p += (size_t)NB * NG * 2 * 4;       // 4 KB
    float* embS  = (float*)p; p += (size_t)NB * NC * 4;           // 16 KB
    f16* qT = (f16*)p;      p += (size_t)NB * NH * HW * HD * 2;   // 16 MB
    f16* kT = (f16*)p;      p += (size_t)NB * NH * HW * HD * 2;   // 16 MB
    f16* vv = (f16*)p;      p += (size_t)NB * NH * HW * HD * 2;   // 16 MB
    f16* oT = (f16*)p;                                            // 16 MB

    gn_stats_k<<<NB * NG, 256, 0, stream>>>(x, stats);
    gn_apply_k<<<dim3(HW / 256, NB), 256, 0, stream>>>(x, stats, nw, nbi, xnT);
    conv_w_k<<<512, 256, 0, stream>>>(in_w, out_w, w_in, w_out);
    gemm_qkv_k<<<dim3(12, 8, NB), 256, 0, stream>>>(w_in, xnT, in_b, qT, kT, vv);
    emb_gemm_k<<<dim3(NC / 4, NB), 256, 0, stream>>>(emb, emb_w, emb_b, embS);
    attn_k<<<512, 256, 0, stream>>>(qT, kT, vv, oT);
    gemm_out_k<<<dim3(NC / 128, HW / 128, NB), 256, 0, stream>>>(w_out, oT, out_b, embS, x, (float*)d_out);
}